// Round 3
// baseline (61.573 us; speedup 1.0000x reference)
//
#include <hip/hip_runtime.h>
#include <float.h>

#define BB 32
#define CC 128
#define HH 64
#define WW 64
#define CHROWS 16   // staged rows per chunk

// Block = 256 threads = 4 waves = 4 consecutive channels of one (b, lmi).
// Each wave stages its channel's clipped ROI window into LDS (dense,
// pow2-padded flat copy -> few line-dense load instructions), then each
// lane (i,j) max-reduces its pooling cell from LDS.
__global__ __launch_bounds__(256) void roipool_kernel(
    const float* __restrict__ x,   // [B,C,64,64]
    const float* __restrict__ lm,  // [B,16]
    float* __restrict__ out)       // [B,C,32,16]
{
    int blk = blockIdx.x;
    int cg  = blk & 31;          // channel group (4 channels)
    int lmi = (blk >> 5) & 7;    // landmark
    int b   = blk >> 8;          // batch

    int wave = threadIdx.x >> 6;
    int lane = threadIdx.x & 63;
    int c = cg * 4 + wave;

    __shared__ float s[4][CHROWS][65];   // +1 pad: adjacent rows shift banks

    float x0 = lm[b * 16 + 2 * lmi];
    float y0 = lm[b * 16 + 2 * lmi + 1];
    bool visible = (x0 > 0.0f) || (y0 > 0.0f);

    // torchvision column-swap semantics:
    // rois=(b,x1,x2,y1,y2) consumed as (b,start_w,start_h,end_w,end_h)
    int fx = (int)floorf(x0 * 0.25f);   // [-5,58]
    int fy = (int)floorf(y0 * 0.25f);
    int roi = max(fy - fx + 1, 1);      // roi_w == roi_h, <= 64
    float bin = (float)roi * 0.125f;    // exact /8

    // clipped window (union of all cells): rows [h0,h1), cols [w0,w1)
    int h0 = min(max(fx, 0), HH);
    int h1 = min(max(fx + roi, 0), HH);
    int w0 = min(max(fx - 7, 0), WW);
    int w1 = min(max(fx - 7 + roi, 0), WW);
    int W  = w1 - w0;                   // <= 64

    // per-cell (output) bounds — same clamps as reference
    int i = lane >> 3;
    int j = lane & 7;
    int hs = min(max((int)floorf((float)i * bin) + fx, 0), HH);
    int he = min(max((int)ceilf((float)(i + 1) * bin) + fx, 0), HH);
    int ws = min(max((int)floorf((float)j * bin) + fx - 7, 0), WW);
    int we = min(max((int)ceilf((float)(j + 1) * bin) + fx - 7, 0), WW);
    bool empty = (he <= hs) || (we <= ws) || !visible;

    float m = -FLT_MAX;
    const float* __restrict__ xp = x + (((size_t)b * CC + c) << 12);

    // Condition depends only on (b,lmi) -> uniform across the block: sync-safe.
    if (visible && W > 0 && h1 > h0) {
        int lg = (W > 1) ? (32 - __clz(W - 1)) : 0;  // W2 = next pow2 >= W
        int W2 = 1 << lg;
        for (int r0 = h0; r0 < h1; r0 += CHROWS) {
            int rn = min(h1 - r0, CHROWS);
            // dense stage: each window row read exactly once, coalesced runs
            for (int idx = lane; idx < rn * W2; idx += 64) {
                int r  = idx >> lg;
                int cc = idx & (W2 - 1);
                if (cc < W)
                    s[wave][r][cc] = xp[(r0 + r) * WW + w0 + cc];
            }
            __syncthreads();
            int lo = max(hs, r0);
            int hi = min(he, r0 + rn);
            for (int h = lo; h < hi; ++h)
                for (int w = ws; w < we; ++w)
                    m = fmaxf(m, s[wave][h - r0][w - w0]);
            __syncthreads();
        }
    }

    float res = empty ? 0.0f : m;
    int orow = 8 * (lmi >> 1) + i;
    int ocol = 8 * (lmi & 1) + j;
    out[(((size_t)b * CC + c) * 32 + orow) * 16 + ocol] = res;
}

extern "C" void kernel_launch(void* const* d_in, const int* in_sizes, int n_in,
                              void* d_out, int out_size, void* d_ws, size_t ws_size,
                              hipStream_t stream) {
    const float* x  = (const float*)d_in[0];
    const float* lm = (const float*)d_in[1];
    float* out = (float*)d_out;

    int blocks = BB * 8 * (CC / 4);   // 8192
    roipool_kernel<<<blocks, 256, 0, stream>>>(x, lm, out);
}

// Round 4
// 31.724 us; speedup vs baseline: 1.9409x; 1.9409x over previous
//
#include <hip/hip_runtime.h>
#include <float.h>

#define BB 32
#define CC 128
#define HH 64
#define WW 64
#define CHB 8   // channels per block

// Block = 256 threads = 4 waves, covering 8 channels of one (b, lmi).
// Grid = 32 * 8 * 16 = 4096 blocks.
__global__ __launch_bounds__(256) void roipool_kernel(
    const float* __restrict__ x,   // [B,C,64,64]
    const float* __restrict__ lm,  // [B,16]
    float* __restrict__ out)       // [B,C,32,16]
{
    int blk = blockIdx.x;
    int g   = blk & 15;          // channel group (8 channels)
    int lmi = (blk >> 4) & 7;    // landmark
    int b   = blk >> 7;          // batch

    int tid  = threadIdx.x;
    int wave = tid >> 6;
    int lane = tid & 63;

    __shared__ float s[CHB][8][65];   // padded: stage-2 same-column reads spread banks

    float x0 = lm[b * 16 + 2 * lmi];
    float y0 = lm[b * 16 + 2 * lmi + 1];
    bool visible = (x0 > 0.0f) || (y0 > 0.0f);

    // torchvision column-swap semantics:
    // rois=(b,x1,x2,y1,y2) consumed as (b,start_w,start_h,end_w,end_h)
    int fx = (int)floorf(x0 * 0.25f);   // [-5,59]
    int fy = (int)floorf(y0 * 0.25f);
    int roi = max(fy - fx + 1, 1);      // roi_w == roi_h
    float bin = (float)roi * 0.125f;    // exact /8

    int cbase = g * CHB;

    // this thread's output cell (stage 2 / stores)
    int i = (lane >> 3);
    int j = lane & 7;
    int orow = 8 * (lmi >> 1) + i;
    int ocol = 8 * (lmi & 1) + j;

    // ---------- fast path: roi==1 -> every cell is pixel (fx, fx-7) ----------
    // (bin=0.125: floor(i*bin)=0, ceil((i+1)*bin)=1 for all i -> all cells identical)
    if (roi == 1) {
        int hs = min(max(fx, 0), HH),     he = min(max(fx + 1, 0), HH);
        int ws = min(max(fx - 7, 0), WW), we = min(max(fx - 6, 0), WW);
        bool empty = (he <= hs) || (we <= ws) || !visible;
        #pragma unroll
        for (int k = 0; k < 2; ++k) {
            int ch = (tid >> 6) + 4 * k;          // 0..7
            size_t c = (size_t)(cbase + ch);
            float v = 0.0f;
            if (!empty) v = x[(((size_t)b * CC + c) << 12) + (hs << 6) + ws];
            out[(((size_t)b * CC + c) * 32 + orow) * 16 + ocol] = v;
        }
        return;   // block-uniform branch: no barrier divergence
    }

    // ---------- stage 1: per-column max per row-bin; wave = 2 channels ----------
    int c0 = cbase + wave * 2;
    const float* __restrict__ xp0 = x + (((size_t)b * CC + c0) << 12) + lane;
    const float* __restrict__ xp1 = xp0 + (1 << 12);

    if (visible) {
        #pragma unroll
        for (int t = 0; t < 8; ++t) {
            int hs = min(max((int)floorf((float)t * bin) + fx, 0), HH);
            int he = min(max((int)ceilf((float)(t + 1) * bin) + fx, 0), HH);
            float a0 = -FLT_MAX, a1 = -FLT_MAX;
            for (int h = hs; h < he; ++h) {       // uniform bounds, coalesced rows
                float v0 = xp0[h << 6];
                float v1 = xp1[h << 6];
                a0 = fmaxf(a0, v0);
                a1 = fmaxf(a1, v1);
            }
            s[c0 - cbase + 0][t][lane] = a0;
            s[c0 - cbase + 1][t][lane] = a1;
        }
    }
    __syncthreads();

    // ---------- stage 2: pool columns from LDS ----------
    int hs = min(max((int)floorf((float)i * bin) + fx, 0), HH);
    int he = min(max((int)ceilf((float)(i + 1) * bin) + fx, 0), HH);
    int ws = min(max((int)floorf((float)j * bin) + fx - 7, 0), WW);
    int we = min(max((int)ceilf((float)(j + 1) * bin) + fx - 7, 0), WW);
    bool empty = (he <= hs) || (we <= ws) || !visible;

    #pragma unroll
    for (int k = 0; k < 2; ++k) {
        int ch = (tid >> 6) + 4 * k;              // 0..7
        float m = -FLT_MAX;
        if (!empty) {
            for (int w = ws; w < we; ++w)
                m = fmaxf(m, s[ch][i][w]);
        }
        out[(((size_t)b * CC + cbase + ch) * 32 + orow) * 16 + ocol] = empty ? 0.0f : m;
    }
}

extern "C" void kernel_launch(void* const* d_in, const int* in_sizes, int n_in,
                              void* d_out, int out_size, void* d_ws, size_t ws_size,
                              hipStream_t stream) {
    const float* x  = (const float*)d_in[0];
    const float* lm = (const float*)d_in[1];
    float* out = (float*)d_out;

    int blocks = BB * 8 * (CC / CHB);   // 4096
    roipool_kernel<<<blocks, 256, 0, stream>>>(x, lm, out);
}

// Round 5
// 24.683 us; speedup vs baseline: 2.4946x; 1.2853x over previous
//
#include <hip/hip_runtime.h>
#include <float.h>

#define BB 32
#define CC 128
#define HH 64
#define WW 64
#define CHB 4   // channels per block; wave = 1 channel

// Block = 256 threads = 4 waves = 4 consecutive channels of one (b, lmi).
// Grid = 32 * 8 * 32 = 8192 blocks.
__global__ __launch_bounds__(256) void roipool_kernel(
    const float* __restrict__ x,   // [B,C,64,64]
    const float* __restrict__ lm,  // [B,16]
    float* __restrict__ out)       // [B,C,32,16]
{
    int blk = blockIdx.x;
    int cg  = blk & 31;          // channel group (4 channels)
    int lmi = (blk >> 5) & 7;    // landmark
    int b   = blk >> 8;          // batch

    int tid  = threadIdx.x;
    int wave = tid >> 6;
    int lane = tid & 63;

    __shared__ float s[CHB][8][65];   // padded

    float x0 = lm[b * 16 + 2 * lmi];
    float y0 = lm[b * 16 + 2 * lmi + 1];
    bool visible = (x0 > 0.0f) || (y0 > 0.0f);

    // torchvision column-swap semantics:
    // rois=(b,x1,x2,y1,y2) consumed as (b,start_w,start_h,end_w,end_h)
    int fx = (int)floorf(x0 * 0.25f);
    int fy = (int)floorf(y0 * 0.25f);
    int roi = max(fy - fx + 1, 1);      // roi_w == roi_h
    float bin = (float)roi * 0.125f;    // exact /8

    int cbase = cg * CHB;

    // this thread's output cell (fast path / stage 2)
    int i = lane >> 3;
    int j = lane & 7;
    int orow = 8 * (lmi >> 1) + i;
    int ocol = 8 * (lmi & 1) + j;

    // ---------- fast path: roi==1 -> every cell is pixel (fx, fx-7) ----------
    if (roi == 1) {
        int hs = min(max(fx, 0), HH),     he = min(max(fx + 1, 0), HH);
        int ws = min(max(fx - 7, 0), WW), we = min(max(fx - 6, 0), WW);
        bool empty = (he <= hs) || (we <= ws) || !visible;
        size_t c = (size_t)(cbase + wave);
        float v = 0.0f;
        if (!empty) v = x[(((size_t)b * CC + c) << 12) + (hs << 6) + ws];
        out[(((size_t)b * CC + c) * 32 + orow) * 16 + ocol] = empty ? 0.0f : v;
        return;   // block-uniform branch
    }

    // ---------- stage 1: per-column max per row-bin; wave = 1 channel ----------
    const float* __restrict__ xp =
        x + (((size_t)b * CC + (cbase + wave)) << 12) + lane;

    if (visible) {
        #pragma unroll
        for (int t = 0; t < 8; ++t) {
            int hs = min(max((int)floorf((float)t * bin) + fx, 0), HH);
            int he = min(max((int)ceilf((float)(t + 1) * bin) + fx, 0), HH);
            float acc = -FLT_MAX;
            for (int h = hs; h < he; h += 4) {
                // clamped duplicate rows are harmless under max; 4 loads in flight
                int h1 = min(h + 1, he - 1);
                int h2 = min(h + 2, he - 1);
                int h3 = min(h + 3, he - 1);
                float v0 = xp[h  << 6];
                float v1 = xp[h1 << 6];
                float v2 = xp[h2 << 6];
                float v3 = xp[h3 << 6];
                acc = fmaxf(acc, fmaxf(fmaxf(v0, v1), fmaxf(v2, v3)));
            }
            s[wave][t][lane] = acc;
        }
    }
    __syncthreads();

    // ---------- stage 2: pool columns from LDS; thread = (channel, cell) ----------
    int hs = min(max((int)floorf((float)i * bin) + fx, 0), HH);
    int he = min(max((int)ceilf((float)(i + 1) * bin) + fx, 0), HH);
    int ws = min(max((int)floorf((float)j * bin) + fx - 7, 0), WW);
    int we = min(max((int)ceilf((float)(j + 1) * bin) + fx - 7, 0), WW);
    bool empty = (he <= hs) || (we <= ws) || !visible;

    float m = -FLT_MAX;
    if (!empty) {
        for (int w = ws; w < we; ++w)
            m = fmaxf(m, s[wave][i][w]);
    }
    out[(((size_t)b * CC + cbase + wave) * 32 + orow) * 16 + ocol] = empty ? 0.0f : m;
}

extern "C" void kernel_launch(void* const* d_in, const int* in_sizes, int n_in,
                              void* d_out, int out_size, void* d_ws, size_t ws_size,
                              hipStream_t stream) {
    const float* x  = (const float*)d_in[0];
    const float* lm = (const float*)d_in[1];
    float* out = (float*)d_out;

    int blocks = BB * 8 * (CC / CHB);   // 8192
    roipool_kernel<<<blocks, 256, 0, stream>>>(x, lm, out);
}